// Round 2
// baseline (2209.494 us; speedup 1.0000x reference)
//
#include <hip/hip_runtime.h>

#define NN 30000
#define EE 480000
#define HH 256
#define TT 4
#define GG 64
#define CC 10
#define MP 30080   // 235 * 128, padded rows

typedef unsigned short u16;
typedef unsigned int u32;
typedef short short8 __attribute__((ext_vector_type(8)));
typedef float f32x4 __attribute__((ext_vector_type(4)));

// ---------- helpers ----------
__device__ __forceinline__ u16 f2bf(float x) {
    u32 u = __float_as_uint(x);
    u32 r = (u + 0x7FFFu + ((u >> 16) & 1u)) >> 16;   // RNE
    return (u16)r;
}
__device__ __forceinline__ float bf2f(u16 h) {
    return __uint_as_float(((u32)h) << 16);
}
__device__ __forceinline__ u32 encf(float x) {       // order-preserving float->uint
    u32 u = __float_as_uint(x);
    return (u & 0x80000000u) ? ~u : (u | 0x80000000u);
}
__device__ __forceinline__ float decf(u32 e) {
    u32 u = (e & 0x80000000u) ? (e ^ 0x80000000u) : ~e;
    return __uint_as_float(u);
}
__device__ __forceinline__ void gl_lds16(const void* g, void* l) {
    __builtin_amdgcn_global_load_lds(
        (const __attribute__((address_space(1))) void*)g,
        (__attribute__((address_space(3))) void*)l, 16, 0, 0);
}

// ---------- conversion / packing kernels ----------
__global__ void k_convert(const float* __restrict__ in, u16* __restrict__ hi,
                          u16* __restrict__ lo, int n) {
    int i = blockIdx.x * 256 + threadIdx.x;
    if (i < n) {
        float v = in[i];
        u16 h = f2bf(v);
        hi[i] = h;
        lo[i] = f2bf(v - bf2f(h));
    }
}

// wrz[j][k] = k<256 ? w_ih[j][k] : w_hh[j][k-256]   (j<512: r,z rows)
__global__ void k_pack_rz(const float* __restrict__ w_ih, const float* __restrict__ w_hh,
                          u16* __restrict__ hi, u16* __restrict__ lo) {
    int i = blockIdx.x * 256 + threadIdx.x;   // over 512*512
    int j = i >> 9, k = i & 511;
    float v = (k < 256) ? w_ih[j * 256 + k] : w_hh[j * 256 + (k - 256)];
    u16 h = f2bf(v);
    hi[i] = h;
    lo[i] = f2bf(v - bf2f(h));
}

__global__ void k_brz(const float* __restrict__ b_ih, const float* __restrict__ b_hh,
                      float* __restrict__ brz) {
    int j = threadIdx.x + blockIdx.x * 256;
    if (j < 512) brz[j] = b_ih[j] + b_hh[j];
}

// h state -> ah cols 256..511 (hi/lo). Padded rows = 0.
__global__ __launch_bounds__(256) void k_feat(const float* __restrict__ feat,
                                              u16* __restrict__ ahHi, u16* __restrict__ ahLo) {
    int n = blockIdx.x, c = threadIdx.x;
    float v = (n < NN) ? feat[(size_t)n * HH + c] : 0.f;
    size_t i = (size_t)n * 512 + 256 + c;
    u16 hb = f2bf(v);
    ahHi[i] = hb;
    ahLo[i] = f2bf(v - bf2f(hb));
}

// ---------- CSR build ----------
__global__ void k_count(const int* __restrict__ dst, int* __restrict__ cnt) {
    int e = blockIdx.x * 256 + threadIdx.x;
    if (e < EE) atomicAdd(&cnt[dst[e]], 1);
}

__global__ __launch_bounds__(1024) void k_scan(const int* __restrict__ cnt,
                                               int* __restrict__ rowptr,
                                               int* __restrict__ cur) {
    __shared__ int buf[1024];
    __shared__ int carry;
    int tid = threadIdx.x;
    if (tid == 0) carry = 0;
    __syncthreads();
    for (int base = 0; base < NN; base += 1024) {
        int x = (base + tid < NN) ? cnt[base + tid] : 0;
        buf[tid] = x;
        __syncthreads();
        for (int ofs = 1; ofs < 1024; ofs <<= 1) {
            int v = (tid >= ofs) ? buf[tid - ofs] : 0;
            __syncthreads();
            buf[tid] += v;
            __syncthreads();
        }
        int excl = buf[tid] - x + carry;
        if (base + tid < NN) { rowptr[base + tid] = excl; cur[base + tid] = excl; }
        int total = buf[1023];
        __syncthreads();
        if (tid == 0) carry += total;
        __syncthreads();
    }
    if (tid == 0) rowptr[NN] = EE;
}

__global__ void k_fill(const int* __restrict__ src, const int* __restrict__ dst,
                       const int* __restrict__ et, int* __restrict__ cur,
                       int* __restrict__ colpk) {
    int e = blockIdx.x * 256 + threadIdx.x;
    if (e < EE) {
        int pos = atomicAdd(&cur[dst[e]], 1);
        colpk[pos] = (et[e] << 16) | src[e];
    }
}

// ---------- split-bf16 MFMA GEMM: C[128y x 128x] = A[. x K] * B[. x K]^T + bias ----------
// 3-term split: Ahi*Bhi + Ahi*Blo + Alo*Bhi  (~fp16-or-better accuracy, fp32 accum)
__global__ __launch_bounds__(256) void gemm_split(
    const u16* __restrict__ Ahi, const u16* __restrict__ Alo, int lda,
    const u16* __restrict__ Bhi, const u16* __restrict__ Blo, int ldb,
    const float* __restrict__ bias, float* __restrict__ C, int ldc, int KT) {
    __shared__ u16 sAh[4096], sAl[4096], sBh[4096], sBl[4096];
    const int tid = threadIdx.x;
    const int lane = tid & 63;
    const int wv = tid >> 6;
    const int wr = wv >> 1, wc = wv & 1;
    const int m0 = blockIdx.y * 128, n0 = blockIdx.x * 128;

    const int ldRow = tid >> 2;
    const int ldK = (tid & 3) * 8;
    const u16* aH = Ahi + (size_t)(m0 + ldRow) * lda + ldK;
    const u16* aL = Alo + (size_t)(m0 + ldRow) * lda + ldK;
    const u16* bH = Bhi + (size_t)(n0 + ldRow) * ldb + ldK;
    const u16* bL = Blo + (size_t)(n0 + ldRow) * ldb + ldK;
    const size_t rstepA = (size_t)64 * lda;
    const size_t rstepB = (size_t)64 * ldb;

    const int wbyte = (tid & ~63) * 16;   // wave-uniform LDS base (lane0 of wave)
    char* dAh = (char*)sAh + wbyte;
    char* dAl = (char*)sAl + wbyte;
    char* dBh = (char*)sBh + wbyte;
    char* dBl = (char*)sBl + wbyte;

    f32x4 acc[4][4];
#pragma unroll
    for (int i = 0; i < 4; i++)
#pragma unroll
        for (int j = 0; j < 4; j++) acc[i][j] = {0.f, 0.f, 0.f, 0.f};

    const int fr = lane & 15;
    const int q8 = (lane >> 4) * 8;

    for (int kt = 0; kt < KT; ++kt) {
        const int k0 = kt * 32;
        __syncthreads();
        gl_lds16(aH + k0, dAh);
        gl_lds16(aH + k0 + rstepA, dAh + 4096);
        gl_lds16(aL + k0, dAl);
        gl_lds16(aL + k0 + rstepA, dAl + 4096);
        gl_lds16(bH + k0, dBh);
        gl_lds16(bH + k0 + rstepB, dBh + 4096);
        gl_lds16(bL + k0, dBl);
        gl_lds16(bL + k0 + rstepB, dBl + 4096);
        __syncthreads();

        short8 bh[4], bl[4];
#pragma unroll
        for (int j = 0; j < 4; j++) {
            int brow = wc * 64 + j * 16 + fr;
            bh[j] = *(const short8*)&sBh[brow * 32 + q8];
            bl[j] = *(const short8*)&sBl[brow * 32 + q8];
        }
#pragma unroll
        for (int i = 0; i < 4; i++) {
            int arow = wr * 64 + i * 16 + fr;
            short8 ah = *(const short8*)&sAh[arow * 32 + q8];
            short8 al = *(const short8*)&sAl[arow * 32 + q8];
#pragma unroll
            for (int j = 0; j < 4; j++) {
                acc[i][j] = __builtin_amdgcn_mfma_f32_16x16x32_bf16(ah, bh[j], acc[i][j], 0, 0, 0);
                acc[i][j] = __builtin_amdgcn_mfma_f32_16x16x32_bf16(ah, bl[j], acc[i][j], 0, 0, 0);
                acc[i][j] = __builtin_amdgcn_mfma_f32_16x16x32_bf16(al, bh[j], acc[i][j], 0, 0, 0);
            }
        }
    }

    // C/D layout (verified m89/m91): col = lane&15, row = (lane>>4)*4 + reg
    const int lr = (lane >> 4) * 4;
    const int lc = lane & 15;
#pragma unroll
    for (int j = 0; j < 4; j++) {
        const int col = n0 + wc * 64 + j * 16 + lc;
        const float bj = bias[col];
#pragma unroll
        for (int i = 0; i < 4; i++) {
            const int rb = m0 + wr * 64 + i * 16 + lr;
#pragma unroll
            for (int r = 0; r < 4; r++)
                C[(size_t)(rb + r) * ldc + col] = acc[i][j][r] + bj;
        }
    }
}

// ---------- per-dst aggregation (pull via CSR, no atomics) -> ah cols 0..255 ----------
__global__ __launch_bounds__(256) void k_agg(const float* __restrict__ Wh,
                                             const int* __restrict__ rowptr,
                                             const int* __restrict__ colpk,
                                             u16* __restrict__ ahHi, u16* __restrict__ ahLo) {
    int n = blockIdx.x, c = threadIdx.x;
    float s = 0.f;
    if (n < NN) {
        int e0 = rowptr[n], e1 = rowptr[n + 1];
        for (int e = e0; e < e1; ++e) {
            int pk = colpk[e];
            int sr = pk & 0xFFFF;
            int t = pk >> 16;
            s += Wh[(size_t)sr * 1024 + t * 256 + c];
        }
    }
    size_t i = (size_t)n * 512 + c;
    u16 hb = f2bf(s);
    ahHi[i] = hb;
    ahLo[i] = f2bf(s - bf2f(hb));
}

// ---------- GRU cell elementwise: G = [rzsum(512) | i_n(256) | h_n(256)] ----------
__global__ __launch_bounds__(256) void k_gru(const float* __restrict__ G,
                                             u16* __restrict__ ahHi, u16* __restrict__ ahLo) {
    int n = blockIdx.x, c = threadIdx.x;
    size_t b = (size_t)n * 1024 + c;
    float rsum = G[b], zsum = G[b + 256], inn = G[b + 512], hn = G[b + 768];
    float r = 1.f / (1.f + expf(-rsum));
    float z = 1.f / (1.f + expf(-zsum));
    float nn = tanhf(inn + r * hn);
    size_t i = (size_t)n * 512 + 256 + c;
    float hv = bf2f(ahHi[i]) + bf2f(ahLo[i]);
    float o = (1.f - z) * nn + z * hv;
    u16 hb = f2bf(o);
    ahHi[i] = hb;
    ahLo[i] = f2bf(o - bf2f(hb));
}

// ---------- tail: elu + BN stats ----------
__global__ __launch_bounds__(256) void k_elu_stats(const u16* __restrict__ ahHi,
                                                   const u16* __restrict__ ahLo,
                                                   float* __restrict__ h2,
                                                   float* __restrict__ bnsum,
                                                   float* __restrict__ bnsq) {
    int c = threadIdx.x;
    int r0 = blockIdx.x * 128;
    int r1 = min(r0 + 128, NN);
    float s = 0.f, q = 0.f;
    for (int n = r0; n < r1; ++n) {
        size_t i = (size_t)n * 512 + 256 + c;
        float x = bf2f(ahHi[i]) + bf2f(ahLo[i]);
        float e = x > 0.f ? x : expm1f(x);
        h2[(size_t)n * HH + c] = e;
        s += e;
        q += e * e;
    }
    atomicAdd(&bnsum[c], s);
    atomicAdd(&bnsq[c], q);
}

// ---------- BN normalize + gate score + segment max ----------
__global__ __launch_bounds__(256) void k_bn_gate(float* __restrict__ h2,
                                                 const float* __restrict__ bnsum,
                                                 const float* __restrict__ bnsq,
                                                 const float* __restrict__ gamma,
                                                 const float* __restrict__ beta,
                                                 const float* __restrict__ gate_w,
                                                 const float* __restrict__ gate_b,
                                                 const int* __restrict__ n2g,
                                                 float* __restrict__ gate,
                                                 u32* __restrict__ gmaxenc) {
    __shared__ float red[256];
    int n = blockIdx.x, c = threadIdx.x;
    float mu = bnsum[c] * (1.f / NN);
    float var = bnsq[c] * (1.f / NN) - mu * mu;
    float x = (h2[(size_t)n * HH + c] - mu) * rsqrtf(var + 1e-5f) * gamma[c] + beta[c];
    h2[(size_t)n * HH + c] = x;
    red[c] = x * gate_w[c];
    __syncthreads();
    for (int st = 128; st > 0; st >>= 1) {
        if (c < st) red[c] += red[c + st];
        __syncthreads();
    }
    if (c == 0) {
        float gt = red[0] + gate_b[0];
        gate[n] = gt;
        atomicMax(&gmaxenc[n2g[n]], encf(gt));
    }
}

// ---------- exp + denom ----------
__global__ void k_expden(float* __restrict__ gate, const int* __restrict__ n2g,
                         const u32* __restrict__ gmaxenc, float* __restrict__ denom) {
    int n = blockIdx.x * 256 + threadIdx.x;
    if (n < NN) {
        int g = n2g[n];
        float e = expf(gate[n] - decf(gmaxenc[g]));
        gate[n] = e;
        atomicAdd(&denom[g], e);
    }
}

// ---------- attention pooling (n2g sorted; flush on graph change) ----------
__global__ __launch_bounds__(256) void k_pool(const float* __restrict__ h2,
                                              const float* __restrict__ gate,
                                              const float* __restrict__ denom,
                                              const int* __restrict__ n2g,
                                              float* __restrict__ h_g) {
    int c = threadIdx.x;
    int r0 = blockIdx.x * 128, r1 = min(r0 + 128, NN);
    int gcur = -1;
    float accv = 0.f, inv = 0.f;
    for (int n = r0; n < r1; ++n) {
        int g = n2g[n];
        if (g != gcur) {
            if (gcur >= 0) atomicAdd(&h_g[gcur * HH + c], accv);
            gcur = g;
            accv = 0.f;
            inv = 1.f / denom[g];
        }
        accv += gate[n] * inv * h2[(size_t)n * HH + c];
    }
    if (gcur >= 0) atomicAdd(&h_g[gcur * HH + c], accv);
}

// ---------- classifier ----------
__global__ __launch_bounds__(256) void k_cls(const float* __restrict__ h_g,
                                             const float* __restrict__ W1,
                                             const float* __restrict__ b1,
                                             const float* __restrict__ W2,
                                             const float* __restrict__ b2,
                                             float* __restrict__ out) {
    __shared__ float hg[256];
    __shared__ float x1[128];
    int g = blockIdx.x, tid = threadIdx.x;
    hg[tid] = h_g[g * HH + tid];
    __syncthreads();
    if (tid < 128) {
        const float* w = W1 + tid * 256;
        float s = b1[tid];
#pragma unroll 8
        for (int c = 0; c < 256; ++c) s += hg[c] * w[c];
        x1[tid] = fmaxf(s, 0.f);
    }
    __syncthreads();
    if (tid < 10) {
        const float* w = W2 + tid * 128;
        float s = b2[tid];
        for (int j = 0; j < 128; ++j) s += x1[j] * w[j];
        out[g * CC + tid] = s;
    }
}

// =======================================================================
extern "C" void kernel_launch(void* const* d_in, const int* in_sizes, int n_in,
                              void* d_out, int out_size, void* d_ws, size_t ws_size,
                              hipStream_t stream) {
    const float* feat  = (const float*)d_in[0];
    const int*   src   = (const int*)d_in[1];
    const int*   dst   = (const int*)d_in[2];
    const int*   etype = (const int*)d_in[3];
    const int*   n2g   = (const int*)d_in[4];
    const float* W_msg = (const float*)d_in[5];
    const float* b_msg = (const float*)d_in[6];
    const float* w_ih  = (const float*)d_in[7];
    const float* w_hh  = (const float*)d_in[8];
    const float* b_ih  = (const float*)d_in[9];
    const float* b_hh  = (const float*)d_in[10];
    const float* bn_g  = (const float*)d_in[11];
    const float* bn_b  = (const float*)d_in[12];
    const float* gatew = (const float*)d_in[13];
    const float* gateb = (const float*)d_in[14];
    const float* W1    = (const float*)d_in[15];
    const float* b1    = (const float*)d_in[16];
    const float* W2    = (const float*)d_in[17];
    const float* b2    = (const float*)d_in[18];
    float* out = (float*)d_out;

    char* ws = (char*)d_ws;
    size_t off = 0;
    auto alloc = [&](size_t bytes) -> char* {
        char* p = ws + off;
        off += (bytes + 255) & ~(size_t)255;
        return p;
    };

    // zero zone (single memset): cnt | bnsum | bnsq | denom | gmaxenc | h_g
    const size_t ZZ = (size_t)(NN + 256 + 256 + 64 + 64 + GG * HH) * 4;
    char* zz = alloc(ZZ);
    int*   cnt     = (int*)zz;
    float* bnsum   = (float*)(zz + (size_t)NN * 4);
    float* bnsq    = bnsum + 256;
    float* denom   = bnsq + 256;
    u32*   gmaxenc = (u32*)(denom + 64);
    float* h_g     = (float*)(gmaxenc + 64);

    int* rowptr = (int*)alloc((NN + 1) * 4);
    int* cur    = (int*)alloc(NN * 4);
    int* colpk  = (int*)alloc((size_t)EE * 4);
    float* gate = (float*)alloc(NN * 4);

    // interleaved node state: cols 0..255 = a, cols 256..511 = h (hi/lo bf16)
    u16* ahHi = (u16*)alloc((size_t)MP * 512 * 2);
    u16* ahLo = (u16*)alloc((size_t)MP * 512 * 2);

    u16* wmsgHi = (u16*)alloc((size_t)1024 * 256 * 2);
    u16* wmsgLo = (u16*)alloc((size_t)1024 * 256 * 2);
    u16* wrzHi  = (u16*)alloc((size_t)512 * 512 * 2);
    u16* wrzLo  = (u16*)alloc((size_t)512 * 512 * 2);
    u16* winHi  = (u16*)alloc((size_t)256 * 256 * 2);
    u16* winLo  = (u16*)alloc((size_t)256 * 256 * 2);
    u16* whnHi  = (u16*)alloc((size_t)256 * 256 * 2);
    u16* whnLo  = (u16*)alloc((size_t)256 * 256 * 2);
    float* brz  = (float*)alloc(512 * 4);

    // big region [MP x 1024] f32: Wh, then (rzsum | i_n | h_n), then h2
    float* big = (float*)alloc((size_t)MP * 1024 * 4);
    float* Wh = big;
    float* G  = big;
    float* h2 = big;

    hipMemsetAsync(zz, 0, ZZ, stream);

    k_convert<<<1024, 256, 0, stream>>>(W_msg, wmsgHi, wmsgLo, 1024 * 256);
    k_convert<<<256, 256, 0, stream>>>(w_ih + 512 * 256, winHi, winLo, 256 * 256);
    k_convert<<<256, 256, 0, stream>>>(w_hh + 512 * 256, whnHi, whnLo, 256 * 256);
    k_pack_rz<<<1024, 256, 0, stream>>>(w_ih, w_hh, wrzHi, wrzLo);
    k_brz<<<2, 256, 0, stream>>>(b_ih, b_hh, brz);
    k_feat<<<MP, 256, 0, stream>>>(feat, ahHi, ahLo);

    k_count<<<(EE + 255) / 256, 256, 0, stream>>>(dst, cnt);
    k_scan<<<1, 1024, 0, stream>>>(cnt, rowptr, cur);
    k_fill<<<(EE + 255) / 256, 256, 0, stream>>>(src, dst, etype, cur, colpk);

    for (int s = 0; s < 5; ++s) {
        // Wh = h * W_msg^T  [MP x 1024]
        gemm_split<<<dim3(8, MP / 128), 256, 0, stream>>>(
            ahHi + 256, ahLo + 256, 512, wmsgHi, wmsgLo, 256, b_msg, Wh, 1024, 8);
        k_agg<<<MP, 256, 0, stream>>>(Wh, rowptr, colpk, ahHi, ahLo);
        // rzsum = [a|h] * [w_ih_rz | w_hh_rz]^T  (K=512) -> G cols 0..511
        gemm_split<<<dim3(4, MP / 128), 256, 0, stream>>>(
            ahHi, ahLo, 512, wrzHi, wrzLo, 512, brz, G, 1024, 16);
        // i_n = a * w_ih_n^T -> G cols 512..767
        gemm_split<<<dim3(2, MP / 128), 256, 0, stream>>>(
            ahHi, ahLo, 512, winHi, winLo, 256, b_ih + 512, G + 512, 1024, 8);
        // h_n = h * w_hh_n^T -> G cols 768..1023
        gemm_split<<<dim3(2, MP / 128), 256, 0, stream>>>(
            ahHi + 256, ahLo + 256, 512, whnHi, whnLo, 256, b_hh + 512, G + 768, 1024, 8);
        k_gru<<<MP, 256, 0, stream>>>(G, ahHi, ahLo);
    }

    k_elu_stats<<<235, 256, 0, stream>>>(ahHi, ahLo, h2, bnsum, bnsq);
    k_bn_gate<<<NN, 256, 0, stream>>>(h2, bnsum, bnsq, bn_g, bn_b, gatew, gateb, n2g, gate, gmaxenc);
    k_expden<<<(NN + 255) / 256, 256, 0, stream>>>(gate, n2g, gmaxenc, denom);
    k_pool<<<235, 256, 0, stream>>>(h2, gate, denom, n2g, h_g);
    k_cls<<<GG, 256, 0, stream>>>(h_g, W1, b1, W2, b2, out);

    (void)in_sizes; (void)n_in; (void)out_size; (void)ws_size;
}